// Round 2
// baseline (260.653 us; speedup 1.0000x reference)
//
#include <hip/hip_runtime.h>
#include <hip/hip_bf16.h>
#include <math.h>

// Problem constants (match reference)
#define BB 8
#define LL 1024
#define DD 1024
#define KK 128
#define NTS 1000
#define NEGF -3.40282346638528859811704183485e38f  // finfo(float32).min
#define SCALE 0.08838834764831845f                 // 128^-0.5

// ---------------------------------------------------------------------------
// Setup kernel: blocks 0..31 -> per-token |pos| norms (8192)
//               blocks 32..35 -> v[d] = sum_c pos_emb_w[c] * pos_feature_w[c,d]
//               block 36 -> resolve is_molecule dtype (int32 vs bool bytes)
// ---------------------------------------------------------------------------
__global__ __launch_bounds__(256) void setup_kernel(
    const float* __restrict__ pos,
    const float* __restrict__ pos_emb_w,
    const float* __restrict__ pos_feature_w,
    const void*  __restrict__ is_mol_raw,
    float* __restrict__ norms,
    float* __restrict__ v,
    int*   __restrict__ is_mol_out)
{
    int gb = blockIdx.x;
    if (gb < 32) {
        int i = gb * 256 + threadIdx.x;           // token index, < 8192
        float x = pos[i * 3 + 0];
        float y = pos[i * 3 + 1];
        float z = pos[i * 3 + 2];
        norms[i] = sqrtf(x * x + y * y + z * z);
    } else if (gb < 36) {
        int d = (gb - 32) * 256 + threadIdx.x;    // dim index, < 1024
        float acc = 0.0f;
        #pragma unroll 4
        for (int c = 0; c < KK; ++c)
            acc += pos_emb_w[c] * pos_feature_w[c * DD + d];
        v[d] = acc;
    } else {
        if (threadIdx.x == 0) {
            // Heuristic: if all BB int32 reads are 0/1 the buffer is int32;
            // otherwise treat it as 1-byte bools. (If the buffer is actually
            // bool-packed this reads 24B past it -- within allocation padding.)
            const int* ip = (const int*)is_mol_raw;
            const unsigned char* cp = (const unsigned char*)is_mol_raw;
            bool all_bin = true;
            for (int i = 0; i < BB; ++i) {
                int x = ip[i];
                if (x != 0 && x != 1) all_bin = false;
            }
            for (int i = 0; i < BB; ++i)
                is_mol_out[i] = all_bin ? (ip[i] != 0) : (cp[i] != 0);
        }
    }
}

// ---------------------------------------------------------------------------
// FP32 tiled GEMM: C[M,N] = op(A[M,K] @ B[K,N] + bias), op = silu if silu!=0
// 64x64 tile, 256 threads, 4x4 per thread, K-step 16.
// No fp32-input MFMA on CDNA4 -> vector-ALU path; keep work minimal instead
// (MLP computed per-timestep [1000 rows], not per-token [8192 rows]).
// ---------------------------------------------------------------------------
__global__ __launch_bounds__(256) void gemm64(
    const float* __restrict__ A, const float* __restrict__ Bm,
    const float* __restrict__ bias, float* __restrict__ C,
    int M, int N, int K, int silu)
{
    __shared__ float As[16][68];   // [k][m]; stride 68 floats = 272B (16B-aligned rows)
    __shared__ float Bs[16][68];   // [k][n]

    const int tid = threadIdx.x;
    const int tx = tid & 15, ty = tid >> 4;
    const int mBase = blockIdx.y * 64, nBase = blockIdx.x * 64;

    float acc[4][4];
    #pragma unroll
    for (int i = 0; i < 4; ++i)
        #pragma unroll
        for (int j = 0; j < 4; ++j) acc[i][j] = 0.0f;

    const int am = tid >> 2, ak = (tid & 3) * 4;   // A tile: 64 rows x 16 k
    const int bk = tid >> 4, bn = (tid & 15) * 4;  // B tile: 16 k x 64 cols
    const int mRow = mBase + am;

    for (int k0 = 0; k0 < K; k0 += 16) {
        float4 av;
        if (mRow < M) av = *(const float4*)&A[(size_t)mRow * K + k0 + ak];
        else          av = make_float4(0.f, 0.f, 0.f, 0.f);
        float4 bv = *(const float4*)&Bm[(size_t)(k0 + bk) * N + nBase + bn];

        As[ak + 0][am] = av.x;
        As[ak + 1][am] = av.y;
        As[ak + 2][am] = av.z;
        As[ak + 3][am] = av.w;
        *(float4*)&Bs[bk][bn] = bv;
        __syncthreads();

        #pragma unroll
        for (int kk = 0; kk < 16; ++kk) {
            float4 a = *(const float4*)&As[kk][ty * 4];
            float4 b = *(const float4*)&Bs[kk][tx * 4];
            acc[0][0] += a.x * b.x; acc[0][1] += a.x * b.y; acc[0][2] += a.x * b.z; acc[0][3] += a.x * b.w;
            acc[1][0] += a.y * b.x; acc[1][1] += a.y * b.y; acc[1][2] += a.y * b.z; acc[1][3] += a.y * b.w;
            acc[2][0] += a.z * b.x; acc[2][1] += a.z * b.y; acc[2][2] += a.z * b.z; acc[2][3] += a.z * b.w;
            acc[3][0] += a.w * b.x; acc[3][1] += a.w * b.y; acc[3][2] += a.w * b.z; acc[3][3] += a.w * b.w;
        }
        __syncthreads();
    }

    #pragma unroll
    for (int i = 0; i < 4; ++i) {
        int m = mBase + ty * 4 + i;
        if (m >= M) continue;
        #pragma unroll
        for (int j = 0; j < 4; ++j) {
            int n = nBase + tx * 4 + j;
            float val = acc[i][j] + bias[n];
            if (silu) val = val / (1.0f + expf(-val));   // x * sigmoid(x)
            C[(size_t)m * N + n] = val;
        }
    }
}

// ---------------------------------------------------------------------------
// Fused output kernel: one block per token (8192 blocks, 256 threads).
// Phase A: s_q = sum_k softmax(dist_q)_k * |pos_k| (norm zeroed at pad keys)
// Phase B: out[q,:] = embed[token] + atom_sum + E[time_step] + (pad?0:s_q)*v
//          out tail: padding_mask as float 0/1
// ---------------------------------------------------------------------------
__global__ __launch_bounds__(256) void fused_out(
    const int*   __restrict__ token_id,
    const int*   __restrict__ node_attr,
    const float* __restrict__ pos,
    const int*   __restrict__ time_step,
    const float* __restrict__ embed_table,
    const float* __restrict__ atom_feat_table,
    const float* __restrict__ E,        // [NTS, D] precomputed time MLP
    const float* __restrict__ v,        // [D]
    const float* __restrict__ norms,    // [B*L]
    const int*   __restrict__ is_mol,   // [B] resolved 0/1
    float* __restrict__ out)
{
    __shared__ float redA[256];
    __shared__ float redB[256];

    const int t   = blockIdx.x;         // token index, < 8192
    const int b   = t >> 10;
    const int tid = threadIdx.x;

    const int token = token_id[t];
    const bool padq = (token == 0);

    // ---- Phase A: attention scalar s_q -------------------------------------
    const float qx = pos[t * 3 + 0];
    const float qy = pos[t * 3 + 1];
    const float qz = pos[t * 3 + 2];

    float dv[4], wv[4];
    float lmax = -INFINITY;
    #pragma unroll
    for (int i = 0; i < 4; ++i) {
        int k = tid + i * 256;
        int kt = token_id[b * LL + k];
        float kx = pos[(b * LL + k) * 3 + 0];
        float ky = pos[(b * LL + k) * 3 + 1];
        float kz = pos[(b * LL + k) * 3 + 2];
        float dx = qx - kx, dy = qy - ky, dz = qz - kz;
        float dn = sqrtf(dx * dx + dy * dy + dz * dz);
        float dist = (padq || kt == 0) ? NEGF : 1.0f / (dn + 1.0f);
        float dsc = dist * SCALE;
        dv[i] = dsc;
        wv[i] = (kt == 0) ? 0.0f : norms[b * LL + k];
        lmax = fmaxf(lmax, dsc);
    }
    // block max reduction
    redA[tid] = lmax;
    __syncthreads();
    for (int off = 128; off > 0; off >>= 1) {
        if (tid < off) redA[tid] = fmaxf(redA[tid], redA[tid + off]);
        __syncthreads();
    }
    const float gmax = redA[0];
    __syncthreads();

    float lsum = 0.0f, lws = 0.0f;
    #pragma unroll
    for (int i = 0; i < 4; ++i) {
        float e = expf(dv[i] - gmax);
        lsum += e;
        lws  += e * wv[i];
    }
    redA[tid] = lsum;
    redB[tid] = lws;
    __syncthreads();
    for (int off = 128; off > 0; off >>= 1) {
        if (tid < off) {
            redA[tid] += redA[tid + off];
            redB[tid] += redB[tid + off];
        }
        __syncthreads();
    }
    const float s = redB[0] / redA[0];

    // ---- Phase B: assemble output ------------------------------------------
    const int ts = time_step[t];
    const int j = tid * 4;                          // 256 threads x float4 = 1024 dims

    float4 acc = *(const float4*)&embed_table[(size_t)token * DD + j];
    if (is_mol[b]) {
        #pragma unroll
        for (int f = 1; f < 9; ++f) {
            int a = node_attr[t * 9 + f];
            float4 av = *(const float4*)&atom_feat_table[(size_t)a * DD + j];
            acc.x += av.x; acc.y += av.y; acc.z += av.z; acc.w += av.w;
        }
    }
    float4 ev = *(const float4*)&E[(size_t)ts * DD + j];
    acc.x += ev.x; acc.y += ev.y; acc.z += ev.z; acc.w += ev.w;

    if (!padq) {
        float4 vv = *(const float4*)&v[j];
        acc.x += s * vv.x; acc.y += s * vv.y; acc.z += s * vv.z; acc.w += s * vv.w;
    }
    *(float4*)&out[(size_t)t * DD + j] = acc;

    if (tid == 0)
        out[(size_t)BB * LL * DD + t] = padq ? 1.0f : 0.0f;
}

// ---------------------------------------------------------------------------
extern "C" void kernel_launch(void* const* d_in, const int* in_sizes, int n_in,
                              void* d_out, int out_size, void* d_ws, size_t ws_size,
                              hipStream_t stream)
{
    const int*   token_id      = (const int*)  d_in[0];
    const int*   node_attr     = (const int*)  d_in[1];
    const void*  is_mol_raw    = (const void*) d_in[2];
    const float* pos           = (const float*)d_in[3];
    const int*   time_step     = (const int*)  d_in[4];
    const float* embed_table   = (const float*)d_in[5];
    const float* atom_feat     = (const float*)d_in[6];
    const float* time_table    = (const float*)d_in[7];
    const float* w1            = (const float*)d_in[8];
    const float* b1            = (const float*)d_in[9];
    const float* w2            = (const float*)d_in[10];
    const float* b2            = (const float*)d_in[11];
    const float* pos_emb_w     = (const float*)d_in[12];
    const float* pos_feature_w = (const float*)d_in[13];

    float* out = (float*)d_out;
    float* W   = (float*)d_ws;

    // Workspace layout (floats): H [1024*1024] | E [1024*1024] | v [1024] |
    //                            norms [8192] | is_mol_res [8 ints]
    // Total ~8.43 MB.
    float* H     = W;
    float* E     = W + 1048576;
    float* V     = W + 2097152;
    float* norms = V + 1024;
    int*   is_mol_res = (int*)(norms + BB * LL);

    setup_kernel<<<37, 256, 0, stream>>>(pos, pos_emb_w, pos_feature_w,
                                         is_mol_raw, norms, V, is_mol_res);

    // Time MLP computed once per timestep (1000 rows), not per token (8192).
    dim3 g(16, 16);  // N/64 x ceil(1000/64)
    gemm64<<<g, 256, 0, stream>>>(time_table, w1, b1, H, NTS, DD, DD, 1);
    gemm64<<<g, 256, 0, stream>>>(H, w2, b2, E, NTS, DD, DD, 0);

    fused_out<<<8192, 256, 0, stream>>>(token_id, node_attr, pos, time_step,
                                        embed_table, atom_feat, E, V, norms,
                                        is_mol_res, out);
}

// Round 3
// 173.073 us; speedup vs baseline: 1.5060x; 1.5060x over previous
//
#include <hip/hip_runtime.h>
#include <hip/hip_bf16.h>
#include <math.h>

// Problem constants (match reference)
#define BB 8
#define LL 1024
#define DD 1024
#define KK 128
#define NTS 1000
#define NEGF -3.40282346638528859811704183485e38f  // finfo(float32).min
#define SCALE 0.08838834764831845f                 // 128^-0.5

typedef __attribute__((ext_vector_type(8))) short short8;   // 8 bf16 = 4 VGPRs
typedef __attribute__((ext_vector_type(4))) float f32x4;    // MFMA accumulator

__device__ __forceinline__ unsigned short f2bf(float x) {
    __hip_bfloat16 h = __float2bfloat16(x);   // RTNE
    return *reinterpret_cast<unsigned short*>(&h);
}

// ---------------------------------------------------------------------------
// Setup kernel: blocks 0..31 -> per-token |pos| norms (8192)
//               blocks 32..35 -> v[d] = sum_c pos_emb_w[c] * pos_feature_w[c,d]
//               block 36 -> resolve is_molecule dtype (int32 vs bool bytes)
// ---------------------------------------------------------------------------
__global__ __launch_bounds__(256) void setup_kernel(
    const float* __restrict__ pos,
    const float* __restrict__ pos_emb_w,
    const float* __restrict__ pos_feature_w,
    const void*  __restrict__ is_mol_raw,
    float* __restrict__ norms,
    float* __restrict__ v,
    int*   __restrict__ is_mol_out)
{
    int gb = blockIdx.x;
    if (gb < 32) {
        int i = gb * 256 + threadIdx.x;           // token index, < 8192
        float x = pos[i * 3 + 0];
        float y = pos[i * 3 + 1];
        float z = pos[i * 3 + 2];
        norms[i] = sqrtf(x * x + y * y + z * z);
    } else if (gb < 36) {
        int d = (gb - 32) * 256 + threadIdx.x;    // dim index, < 1024
        float acc = 0.0f;
        #pragma unroll 4
        for (int c = 0; c < KK; ++c)
            acc += pos_emb_w[c] * pos_feature_w[c * DD + d];
        v[d] = acc;
    } else {
        if (threadIdx.x == 0) {
            const int* ip = (const int*)is_mol_raw;
            const unsigned char* cp = (const unsigned char*)is_mol_raw;
            bool all_bin = true;
            for (int i = 0; i < BB; ++i) {
                int x = ip[i];
                if (x != 0 && x != 1) all_bin = false;
            }
            for (int i = 0; i < BB; ++i)
                is_mol_out[i] = all_bin ? (ip[i] != 0) : (cp[i] != 0);
        }
    }
}

// ---------------------------------------------------------------------------
// Cast time_table [1000,1024] fp32 -> bf16 [1024,1024], rows 1000..1023 zeroed
// (padding rows let the GEMM drop all M-bounds checks; garbage E rows are
// never gathered since time_step < 1000).
// ---------------------------------------------------------------------------
__global__ __launch_bounds__(256) void cast_pad_kernel(
    const float* __restrict__ in, unsigned short* __restrict__ out)
{
    int i = blockIdx.x * 256 + threadIdx.x;       // over 1024*1024/4 = 262144
    int e = i * 4;
    ushort4 o;
    if (e < NTS * DD) {
        float4 vv = *(const float4*)&in[e];
        o.x = f2bf(vv.x); o.y = f2bf(vv.y); o.z = f2bf(vv.z); o.w = f2bf(vv.w);
    } else {
        o.x = o.y = o.z = o.w = 0;
    }
    *(ushort4*)&out[e] = o;
}

// ---------------------------------------------------------------------------
// Transpose + cast: in [1024,1024] fp32 row-major -> out[n][k] bf16
// (MFMA B-fragment wants 8 contiguous k for fixed n -> store B transposed.)
// 32x32 LDS tile, 256 threads.
// ---------------------------------------------------------------------------
__global__ __launch_bounds__(256) void transpose_cast_kernel(
    const float* __restrict__ in, unsigned short* __restrict__ out)
{
    __shared__ float tile[32][33];
    const int tx = threadIdx.x & 31, ty = threadIdx.x >> 5;   // 32 x 8
    const int bx = blockIdx.x * 32, by = blockIdx.y * 32;
    #pragma unroll
    for (int r = 0; r < 32; r += 8)
        tile[ty + r][tx] = in[(size_t)(by + ty + r) * DD + bx + tx];
    __syncthreads();
    #pragma unroll
    for (int r = 0; r < 32; r += 8)
        out[(size_t)(bx + ty + r) * DD + by + tx] = f2bf(tile[tx][ty + r]);
}

// ---------------------------------------------------------------------------
// bf16 MFMA GEMM: C[1024,1024] = op(A @ B + bias)
//   A  [1024,1024] bf16 row-major (k contiguous)
//   Bt [1024,1024] bf16, Bt[n][k]  (k contiguous)
// Block: 256 thr = 4 waves, tile 64x64, wave-tile 32x32 (2x2 frags 16x16),
// BK=64. MODE 0: silu -> bf16 out (H). MODE 1: bias only -> fp32 out (E).
// Grid 16x16 = 256 blocks = 1/CU; LDS-throughput bound, ~2-4 us predicted.
// ---------------------------------------------------------------------------
template <int MODE>
__global__ __launch_bounds__(256) void mfma_gemm(
    const unsigned short* __restrict__ A,
    const unsigned short* __restrict__ Bt,
    const float* __restrict__ bias,
    void* __restrict__ Cout)
{
    // +8 pad: row stride 144B keeps 16B alignment, spreads b128 reads evenly
    __shared__ __align__(16) unsigned short As[64][72];
    __shared__ __align__(16) unsigned short Bs[64][72];

    const int tid  = threadIdx.x;
    const int lane = tid & 63;
    const int wave = tid >> 6;
    const int wm = wave >> 1, wn = wave & 1;          // 2x2 wave grid
    const int quad = lane >> 4, l16 = lane & 15;
    const int mBase = blockIdx.y * 64, nBase = blockIdx.x * 64;

    f32x4 acc[2][2] = {{{0.f,0.f,0.f,0.f},{0.f,0.f,0.f,0.f}},
                       {{0.f,0.f,0.f,0.f},{0.f,0.f,0.f,0.f}}};

    // staging: 512 16B-chunks per operand tile (64 rows x 8 chunks), 2/thread
    const int r0 = tid >> 3,           ko0 = (tid & 7) << 3;
    const int r1 = (tid + 256) >> 3,   ko1 = ko0;      // chunk c+256: same ko, row+32

    for (int k0 = 0; k0 < DD; k0 += 64) {
        float4 a0 = *(const float4*)&A [(size_t)(mBase + r0) * DD + k0 + ko0];
        float4 a1 = *(const float4*)&A [(size_t)(mBase + r1) * DD + k0 + ko1];
        float4 b0 = *(const float4*)&Bt[(size_t)(nBase + r0) * DD + k0 + ko0];
        float4 b1 = *(const float4*)&Bt[(size_t)(nBase + r1) * DD + k0 + ko1];
        *(float4*)&As[r0][ko0] = a0;
        *(float4*)&As[r1][ko1] = a1;
        *(float4*)&Bs[r0][ko0] = b0;
        *(float4*)&Bs[r1][ko1] = b1;
        __syncthreads();

        #pragma unroll
        for (int kk = 0; kk < 64; kk += 32) {
            short8 af0 = *(const short8*)&As[wm * 32 +      l16][kk + quad * 8];
            short8 af1 = *(const short8*)&As[wm * 32 + 16 + l16][kk + quad * 8];
            short8 bf0 = *(const short8*)&Bs[wn * 32 +      l16][kk + quad * 8];
            short8 bf1 = *(const short8*)&Bs[wn * 32 + 16 + l16][kk + quad * 8];
            acc[0][0] = __builtin_amdgcn_mfma_f32_16x16x32_bf16(af0, bf0, acc[0][0], 0, 0, 0);
            acc[0][1] = __builtin_amdgcn_mfma_f32_16x16x32_bf16(af0, bf1, acc[0][1], 0, 0, 0);
            acc[1][0] = __builtin_amdgcn_mfma_f32_16x16x32_bf16(af1, bf0, acc[1][0], 0, 0, 0);
            acc[1][1] = __builtin_amdgcn_mfma_f32_16x16x32_bf16(af1, bf1, acc[1][1], 0, 0, 0);
        }
        __syncthreads();
    }

    // Epilogue. C/D layout: col = lane&15, row = quad*4 + reg  [m89-verified]
    #pragma unroll
    for (int mi = 0; mi < 2; ++mi) {
        #pragma unroll
        for (int ni = 0; ni < 2; ++ni) {
            const int col = nBase + wn * 32 + ni * 16 + l16;
            const float bv = bias[col];
            #pragma unroll
            for (int r = 0; r < 4; ++r) {
                const int row = mBase + wm * 32 + mi * 16 + quad * 4 + r;
                float val = acc[mi][ni][r] + bv;
                if (MODE == 0) {
                    val = val / (1.0f + expf(-val));           // silu
                    ((unsigned short*)Cout)[(size_t)row * DD + col] = f2bf(val);
                } else {
                    ((float*)Cout)[(size_t)row * DD + col] = val;
                }
            }
        }
    }
}

// ---------------------------------------------------------------------------
// Fused output kernel: one block per token (8192 blocks, 256 threads).
// Phase A: s_q = sum_k softmax(dist_q)_k * |pos_k| (norm zeroed at pad keys)
// Phase B: out[q,:] = embed[token] + atom_sum + E[time_step] + (pad?0:s_q)*v
//          out tail: padding_mask as float 0/1
// ---------------------------------------------------------------------------
__global__ __launch_bounds__(256) void fused_out(
    const int*   __restrict__ token_id,
    const int*   __restrict__ node_attr,
    const float* __restrict__ pos,
    const int*   __restrict__ time_step,
    const float* __restrict__ embed_table,
    const float* __restrict__ atom_feat_table,
    const float* __restrict__ E,        // [NTS, D] precomputed time MLP
    const float* __restrict__ v,        // [D]
    const float* __restrict__ norms,    // [B*L]
    const int*   __restrict__ is_mol,   // [B] resolved 0/1
    float* __restrict__ out)
{
    __shared__ float redA[256];
    __shared__ float redB[256];

    const int t   = blockIdx.x;         // token index, < 8192
    const int b   = t >> 10;
    const int tid = threadIdx.x;

    const int token = token_id[t];
    const bool padq = (token == 0);

    // ---- Phase A: attention scalar s_q -------------------------------------
    const float qx = pos[t * 3 + 0];
    const float qy = pos[t * 3 + 1];
    const float qz = pos[t * 3 + 2];

    float dv[4], wv[4];
    float lmax = -INFINITY;
    #pragma unroll
    for (int i = 0; i < 4; ++i) {
        int k = tid + i * 256;
        int kt = token_id[b * LL + k];
        float kx = pos[(b * LL + k) * 3 + 0];
        float ky = pos[(b * LL + k) * 3 + 1];
        float kz = pos[(b * LL + k) * 3 + 2];
        float dx = qx - kx, dy = qy - ky, dz = qz - kz;
        float dn = sqrtf(dx * dx + dy * dy + dz * dz);
        float dist = (padq || kt == 0) ? NEGF : 1.0f / (dn + 1.0f);
        float dsc = dist * SCALE;
        dv[i] = dsc;
        wv[i] = (kt == 0) ? 0.0f : norms[b * LL + k];
        lmax = fmaxf(lmax, dsc);
    }
    redA[tid] = lmax;
    __syncthreads();
    for (int off = 128; off > 0; off >>= 1) {
        if (tid < off) redA[tid] = fmaxf(redA[tid], redA[tid + off]);
        __syncthreads();
    }
    const float gmax = redA[0];
    __syncthreads();

    float lsum = 0.0f, lws = 0.0f;
    #pragma unroll
    for (int i = 0; i < 4; ++i) {
        float e = expf(dv[i] - gmax);
        lsum += e;
        lws  += e * wv[i];
    }
    redA[tid] = lsum;
    redB[tid] = lws;
    __syncthreads();
    for (int off = 128; off > 0; off >>= 1) {
        if (tid < off) {
            redA[tid] += redA[tid + off];
            redB[tid] += redB[tid + off];
        }
        __syncthreads();
    }
    const float s = redB[0] / redA[0];

    // ---- Phase B: assemble output ------------------------------------------
    const int ts = time_step[t];
    const int j = tid * 4;

    float4 acc = *(const float4*)&embed_table[(size_t)token * DD + j];
    if (is_mol[b]) {
        #pragma unroll
        for (int f = 1; f < 9; ++f) {
            int a = node_attr[t * 9 + f];
            float4 av = *(const float4*)&atom_feat_table[(size_t)a * DD + j];
            acc.x += av.x; acc.y += av.y; acc.z += av.z; acc.w += av.w;
        }
    }
    float4 ev = *(const float4*)&E[(size_t)ts * DD + j];
    acc.x += ev.x; acc.y += ev.y; acc.z += ev.z; acc.w += ev.w;

    if (!padq) {
        float4 vv = *(const float4*)&v[j];
        acc.x += s * vv.x; acc.y += s * vv.y; acc.z += s * vv.z; acc.w += s * vv.w;
    }
    *(float4*)&out[(size_t)t * DD + j] = acc;

    if (tid == 0)
        out[(size_t)BB * LL * DD + t] = padq ? 1.0f : 0.0f;
}

// ---------------------------------------------------------------------------
extern "C" void kernel_launch(void* const* d_in, const int* in_sizes, int n_in,
                              void* d_out, int out_size, void* d_ws, size_t ws_size,
                              hipStream_t stream)
{
    const int*   token_id      = (const int*)  d_in[0];
    const int*   node_attr     = (const int*)  d_in[1];
    const void*  is_mol_raw    = (const void*) d_in[2];
    const float* pos           = (const float*)d_in[3];
    const int*   time_step     = (const int*)  d_in[4];
    const float* embed_table   = (const float*)d_in[5];
    const float* atom_feat     = (const float*)d_in[6];
    const float* time_table    = (const float*)d_in[7];
    const float* w1            = (const float*)d_in[8];
    const float* b1            = (const float*)d_in[9];
    const float* w2            = (const float*)d_in[10];
    const float* b2            = (const float*)d_in[11];
    const float* pos_emb_w     = (const float*)d_in[12];
    const float* pos_feature_w = (const float*)d_in[13];

    float* out = (float*)d_out;
    float* Wf  = (float*)d_ws;

    // Workspace overlay (floats), total ~8.08 MB:
    //   [0 .. 1048576):  phase 1: Tbf (bf16, 2MB) + W1t (bf16, 2MB)
    //                    phase 2 (after GEMM1): E (fp32, 4MB)
    //   [1048576 .. 2097152): H (bf16, 2MB) + W2t (bf16, 2MB)
    //   then V[1024], norms[8192], is_mol[8]
    unsigned short* Tbf = (unsigned short*)Wf;
    unsigned short* W1t = (unsigned short*)(Wf + 524288);
    float*          E   = Wf;
    unsigned short* H   = (unsigned short*)(Wf + 1048576);
    unsigned short* W2t = (unsigned short*)(Wf + 1048576 + 524288);
    float* V     = Wf + 2097152;
    float* norms = V + 1024;
    int*   is_mol_res = (int*)(norms + BB * LL);

    setup_kernel<<<37, 256, 0, stream>>>(pos, pos_emb_w, pos_feature_w,
                                         is_mol_raw, norms, V, is_mol_res);
    cast_pad_kernel<<<1024, 256, 0, stream>>>(time_table, Tbf);
    transpose_cast_kernel<<<dim3(32, 32), 256, 0, stream>>>(w1, W1t);
    transpose_cast_kernel<<<dim3(32, 32), 256, 0, stream>>>(w2, W2t);

    // Time MLP on matrix cores, once per timestep (padded to 1024 rows).
    dim3 g(16, 16);
    mfma_gemm<0><<<g, 256, 0, stream>>>(Tbf, W1t, b1, (void*)H);
    mfma_gemm<1><<<g, 256, 0, stream>>>(H, W2t, b2, (void*)E);

    fused_out<<<8192, 256, 0, stream>>>(token_id, node_attr, pos, time_step,
                                        embed_table, atom_feat, E, V, norms,
                                        is_mol_res, out);
}

// Round 4
// 158.641 us; speedup vs baseline: 1.6430x; 1.0910x over previous
//
#include <hip/hip_runtime.h>
#include <hip/hip_bf16.h>
#include <math.h>

// Problem constants (match reference)
#define BB 8
#define LL 1024
#define DD 1024
#define KK 128
#define NTS 1000
#define SCALE 0.08838834764831845f                 // 128^-0.5

typedef __attribute__((ext_vector_type(8))) short short8;   // 8 bf16 = 4 VGPRs
typedef __attribute__((ext_vector_type(4))) float f32x4;    // MFMA accumulator

__device__ __forceinline__ unsigned short f2bf(float x) {
    __hip_bfloat16 h = __float2bfloat16(x);   // RTNE
    return *reinterpret_cast<unsigned short*>(&h);
}

// ---------------------------------------------------------------------------
// Merged prep kernel (one dispatch):
//   blocks    0..1023 : cast time_table fp32 -> bf16 [1024,1024], pad rows 0
//   blocks 1024..2047 : transpose+cast w1 -> W1t[n][k] bf16
//   blocks 2048..3071 : transpose+cast w2 -> W2t[n][k] bf16
//   blocks 3072..3075 : v[d] = sum_c pos_emb_w[c] * pos_feature_w[c,d]
//   block  3076       : resolve is_molecule dtype (int32 vs bool bytes)
// ---------------------------------------------------------------------------
__global__ __launch_bounds__(256) void prep_kernel(
    const float* __restrict__ time_table,
    const float* __restrict__ w1,
    const float* __restrict__ w2,
    const float* __restrict__ pos_emb_w,
    const float* __restrict__ pos_feature_w,
    const void*  __restrict__ is_mol_raw,
    unsigned short* __restrict__ Tbf,
    unsigned short* __restrict__ W1t,
    unsigned short* __restrict__ W2t,
    float* __restrict__ v,
    int*   __restrict__ is_mol_out)
{
    __shared__ float tile[32][33];
    const int blk = blockIdx.x;

    if (blk < 1024) {
        // cast + zero-pad rows 1000..1023
        int e = (blk * 256 + threadIdx.x) * 4;
        ushort4 o;
        if (e < NTS * DD) {
            float4 vv = *(const float4*)&time_table[e];
            o.x = f2bf(vv.x); o.y = f2bf(vv.y); o.z = f2bf(vv.z); o.w = f2bf(vv.w);
        } else {
            o.x = o.y = o.z = o.w = 0;
        }
        *(ushort4*)&Tbf[e] = o;
    } else if (blk < 3072) {
        const int which = (blk - 1024) >> 10;          // 0 -> w1, 1 -> w2
        const int idx = (blk - 1024) & 1023;
        const float* in = which ? w2 : w1;
        unsigned short* out = which ? W2t : W1t;
        const int bx = (idx & 31) * 32, by = (idx >> 5) * 32;
        const int tx = threadIdx.x & 31, ty = threadIdx.x >> 5;  // 32 x 8
        #pragma unroll
        for (int r = 0; r < 32; r += 8)
            tile[ty + r][tx] = in[(size_t)(by + ty + r) * DD + bx + tx];
        __syncthreads();
        #pragma unroll
        for (int r = 0; r < 32; r += 8)
            out[(size_t)(bx + ty + r) * DD + by + tx] = f2bf(tile[tx][ty + r]);
    } else if (blk < 3076) {
        int d = (blk - 3072) * 256 + threadIdx.x;      // < 1024
        float acc = 0.0f;
        #pragma unroll 4
        for (int c = 0; c < KK; ++c)
            acc += pos_emb_w[c] * pos_feature_w[c * DD + d];
        v[d] = acc;
    } else {
        if (threadIdx.x == 0) {
            const int* ip = (const int*)is_mol_raw;
            const unsigned char* cp = (const unsigned char*)is_mol_raw;
            bool all_bin = true;
            for (int i = 0; i < BB; ++i) {
                int x = ip[i];
                if (x != 0 && x != 1) all_bin = false;
            }
            for (int i = 0; i < BB; ++i)
                is_mol_out[i] = all_bin ? (ip[i] != 0) : (cp[i] != 0);
        }
    }
}

// ---------------------------------------------------------------------------
// bf16 MFMA GEMM: C[1024,1024] = op(A @ B + bias)  (unchanged from R2)
//   A  [1024,1024] bf16 row-major; Bt [1024,1024] bf16, Bt[n][k]
// 256 thr = 4 waves, tile 64x64, wave-tile 32x32, BK=64.
// MODE 0: silu -> bf16 out (H). MODE 1: bias only -> fp32 out (E).
// ---------------------------------------------------------------------------
template <int MODE>
__global__ __launch_bounds__(256) void mfma_gemm(
    const unsigned short* __restrict__ A,
    const unsigned short* __restrict__ Bt,
    const float* __restrict__ bias,
    void* __restrict__ Cout)
{
    __shared__ __align__(16) unsigned short As[64][72];
    __shared__ __align__(16) unsigned short Bs[64][72];

    const int tid  = threadIdx.x;
    const int lane = tid & 63;
    const int wave = tid >> 6;
    const int wm = wave >> 1, wn = wave & 1;
    const int quad = lane >> 4, l16 = lane & 15;
    const int mBase = blockIdx.y * 64, nBase = blockIdx.x * 64;

    f32x4 acc[2][2] = {{{0.f,0.f,0.f,0.f},{0.f,0.f,0.f,0.f}},
                       {{0.f,0.f,0.f,0.f},{0.f,0.f,0.f,0.f}}};

    const int r0 = tid >> 3,         ko0 = (tid & 7) << 3;
    const int r1 = (tid + 256) >> 3, ko1 = ko0;

    for (int k0 = 0; k0 < DD; k0 += 64) {
        float4 a0 = *(const float4*)&A [(size_t)(mBase + r0) * DD + k0 + ko0];
        float4 a1 = *(const float4*)&A [(size_t)(mBase + r1) * DD + k0 + ko1];
        float4 b0 = *(const float4*)&Bt[(size_t)(nBase + r0) * DD + k0 + ko0];
        float4 b1 = *(const float4*)&Bt[(size_t)(nBase + r1) * DD + k0 + ko1];
        *(float4*)&As[r0][ko0] = a0;
        *(float4*)&As[r1][ko1] = a1;
        *(float4*)&Bs[r0][ko0] = b0;
        *(float4*)&Bs[r1][ko1] = b1;
        __syncthreads();

        #pragma unroll
        for (int kk = 0; kk < 64; kk += 32) {
            short8 af0 = *(const short8*)&As[wm * 32 +      l16][kk + quad * 8];
            short8 af1 = *(const short8*)&As[wm * 32 + 16 + l16][kk + quad * 8];
            short8 bf0 = *(const short8*)&Bs[wn * 32 +      l16][kk + quad * 8];
            short8 bf1 = *(const short8*)&Bs[wn * 32 + 16 + l16][kk + quad * 8];
            acc[0][0] = __builtin_amdgcn_mfma_f32_16x16x32_bf16(af0, bf0, acc[0][0], 0, 0, 0);
            acc[0][1] = __builtin_amdgcn_mfma_f32_16x16x32_bf16(af0, bf1, acc[0][1], 0, 0, 0);
            acc[1][0] = __builtin_amdgcn_mfma_f32_16x16x32_bf16(af1, bf0, acc[1][0], 0, 0, 0);
            acc[1][1] = __builtin_amdgcn_mfma_f32_16x16x32_bf16(af1, bf1, acc[1][1], 0, 0, 0);
        }
        __syncthreads();
    }

    // C/D layout: col = lane&15, row = quad*4 + reg  [m89-verified]
    #pragma unroll
    for (int mi = 0; mi < 2; ++mi) {
        #pragma unroll
        for (int ni = 0; ni < 2; ++ni) {
            const int col = nBase + wn * 32 + ni * 16 + l16;
            const float bv = bias[col];
            #pragma unroll
            for (int r = 0; r < 4; ++r) {
                const int row = mBase + wm * 32 + mi * 16 + quad * 4 + r;
                float val = acc[mi][ni][r] + bv;
                if (MODE == 0) {
                    val = val / (1.0f + expf(-val));           // silu
                    ((unsigned short*)Cout)[(size_t)row * DD + col] = f2bf(val);
                } else {
                    ((float*)Cout)[(size_t)row * DD + col] = val;
                }
            }
        }
    }
}

// ---------------------------------------------------------------------------
// Fused attention + assembly: 1024 blocks x 256 thr; block = 8 queries of one
// batch. Keys staged once in LDS as float4(kx,ky,kz,w_s), w_s = pad? -1 : |pos|.
// No-max softmax: scores in (0, 0.0884] so exp can't overflow; masked keys
// contribute exactly 0 (matching exp(NEG*SCALE - gmax) == 0 in the reference).
// Phase A per wave: 2 queries, LDS scan + shfl_xor butterfly (no barriers).
// Phase B per query: out = embed[tok] + atom_sum + E[ts] + s*v; mask tail.
// ---------------------------------------------------------------------------
__global__ __launch_bounds__(256) void fused_all(
    const int*   __restrict__ token_id,
    const int*   __restrict__ node_attr,
    const float* __restrict__ pos,
    const int*   __restrict__ time_step,
    const float* __restrict__ embed_table,
    const float* __restrict__ atom_feat_table,
    const float* __restrict__ E,        // [1024, D] time MLP (rows >=1000 junk)
    const float* __restrict__ v,        // [D]
    const int*   __restrict__ is_mol,   // [B] resolved 0/1
    float* __restrict__ out)
{
    __shared__ float4 keys[LL];         // 16 KB
    __shared__ float  sS[8];

    const int blk   = blockIdx.x;       // 0..1023
    const int batch = blk >> 7;
    const int q0    = (blk & 127) << 3; // 8 queries per block
    const int tid   = threadIdx.x;
    const int lane  = tid & 63, wave = tid >> 6;

    // ---- stage keys --------------------------------------------------------
    #pragma unroll
    for (int i = 0; i < 4; ++i) {
        const int k = tid + i * 256;
        const int t = batch * LL + k;
        const float x = pos[t * 3 + 0];
        const float y = pos[t * 3 + 1];
        const float z = pos[t * 3 + 2];
        const int tok = token_id[t];
        const float n = sqrtf(x * x + y * y + z * z);
        keys[k] = make_float4(x, y, z, tok == 0 ? -1.0f : n);
    }
    __syncthreads();

    // ---- Phase A: s per query (wave handles 2 queries) ---------------------
    #pragma unroll
    for (int qi = 0; qi < 2; ++qi) {
        const int ql = wave * 2 + qi;
        const float4 qk = keys[q0 + ql];          // broadcast read
        float lsum = 0.0f, lws = 0.0f;
        #pragma unroll 4
        for (int i = 0; i < 16; ++i) {
            const float4 kd = keys[lane + i * 64];
            const float dx = qk.x - kd.x, dy = qk.y - kd.y, dz = qk.z - kd.z;
            const float dn = sqrtf(dx * dx + dy * dy + dz * dz);
            const float e = __expf(SCALE / (dn + 1.0f));
            const bool valid = kd.w >= 0.0f;
            const float ev = valid ? e : 0.0f;
            lsum += ev;
            lws  += ev * (valid ? kd.w : 0.0f);
        }
        #pragma unroll
        for (int off = 32; off > 0; off >>= 1) {
            lsum += __shfl_xor(lsum, off);
            lws  += __shfl_xor(lws,  off);
        }
        if (lane == 0)
            sS[ql] = (qk.w < 0.0f) ? 0.0f : (lws / lsum);  // pad query: s unused -> 0
    }
    __syncthreads();

    // ---- Phase B: assemble 8 output rows -----------------------------------
    const int im = is_mol[batch];
    const int j  = tid * 4;
    const float4 vv = *(const float4*)&v[j];

    for (int ql = 0; ql < 8; ++ql) {
        const int t   = batch * LL + q0 + ql;
        const int tok = token_id[t];
        const int ts  = time_step[t];
        const float s = sS[ql];

        float4 acc = *(const float4*)&embed_table[(size_t)tok * DD + j];
        if (im) {
            #pragma unroll
            for (int f = 1; f < 9; ++f) {
                const int a = node_attr[t * 9 + f];
                const float4 av = *(const float4*)&atom_feat_table[(size_t)a * DD + j];
                acc.x += av.x; acc.y += av.y; acc.z += av.z; acc.w += av.w;
            }
        }
        const float4 ev = *(const float4*)&E[(size_t)ts * DD + j];
        acc.x += ev.x + s * vv.x;
        acc.y += ev.y + s * vv.y;
        acc.z += ev.z + s * vv.z;
        acc.w += ev.w + s * vv.w;
        *(float4*)&out[(size_t)t * DD + j] = acc;
    }

    if (tid < 8) {
        const int t = batch * LL + q0 + tid;
        out[(size_t)BB * LL * DD + t] = (keys[q0 + tid].w < 0.0f) ? 1.0f : 0.0f;
    }
}

// ---------------------------------------------------------------------------
extern "C" void kernel_launch(void* const* d_in, const int* in_sizes, int n_in,
                              void* d_out, int out_size, void* d_ws, size_t ws_size,
                              hipStream_t stream)
{
    const int*   token_id      = (const int*)  d_in[0];
    const int*   node_attr     = (const int*)  d_in[1];
    const void*  is_mol_raw    = (const void*) d_in[2];
    const float* pos           = (const float*)d_in[3];
    const int*   time_step     = (const int*)  d_in[4];
    const float* embed_table   = (const float*)d_in[5];
    const float* atom_feat     = (const float*)d_in[6];
    const float* time_table    = (const float*)d_in[7];
    const float* w1            = (const float*)d_in[8];
    const float* b1            = (const float*)d_in[9];
    const float* w2            = (const float*)d_in[10];
    const float* b2            = (const float*)d_in[11];
    const float* pos_emb_w     = (const float*)d_in[12];
    const float* pos_feature_w = (const float*)d_in[13];

    float* out = (float*)d_out;
    float* Wf  = (float*)d_ws;

    // Workspace overlay (floats), ~8.4 MB:
    //   [0 .. 1048576):  phase 1: Tbf (bf16 2MB) + W1t (bf16 2MB)
    //                    phase 2 (after GEMM1 consumed them): E (fp32 4MB)
    //   [1048576 .. 2097152): H (bf16 2MB) + W2t (bf16 2MB)
    //   [2097152 ..): V[1024] fp32, is_mol[8] int
    unsigned short* Tbf = (unsigned short*)Wf;
    unsigned short* W1t = (unsigned short*)(Wf + 524288);
    float*          E   = Wf;
    unsigned short* H   = (unsigned short*)(Wf + 1048576);
    unsigned short* W2t = (unsigned short*)(Wf + 1048576 + 524288);
    float* V     = Wf + 2097152;
    int*   is_mol_res = (int*)(V + 1024);

    prep_kernel<<<3077, 256, 0, stream>>>(time_table, w1, w2, pos_emb_w,
                                          pos_feature_w, is_mol_raw,
                                          Tbf, W1t, W2t, V, is_mol_res);

    dim3 g(16, 16);
    mfma_gemm<0><<<g, 256, 0, stream>>>(Tbf, W1t, b1, (void*)H);
    mfma_gemm<1><<<g, 256, 0, stream>>>(H, W2t, b2, (void*)E);

    fused_all<<<1024, 256, 0, stream>>>(token_id, node_attr, pos, time_step,
                                        embed_table, atom_feat, E, V,
                                        is_mol_res, out);
}

// Round 5
// 151.744 us; speedup vs baseline: 1.7177x; 1.0455x over previous
//
#include <hip/hip_runtime.h>
#include <hip/hip_bf16.h>
#include <math.h>

// Problem constants (match reference)
#define BB 8
#define LL 1024
#define DD 1024
#define KK 128
#define NTS 1000
#define VOCAB 160
#define NATOM 512
#define SCALE 0.08838834764831845f                 // 128^-0.5

typedef __attribute__((ext_vector_type(8))) short short8;   // 8 bf16 = 4 VGPRs
typedef __attribute__((ext_vector_type(4))) float f32x4;    // MFMA accumulator

__device__ __forceinline__ unsigned short f2bf(float x) {
    __hip_bfloat16 h = __float2bfloat16(x);   // RTNE
    return *reinterpret_cast<unsigned short*>(&h);
}
__device__ __forceinline__ float bf2f(unsigned short u) {
    return __uint_as_float(((unsigned int)u) << 16);
}

// ---------------------------------------------------------------------------
// Merged prep kernel (one dispatch, 2725 blocks):
//   0..2047    : transpose+cast w1 / w2 -> W1t/W2t [n][k] bf16
//   2048..2207 : cast embed_table fp32 -> bf16 (160*1024 elems)
//   2208..2719 : cast atom_feat_table fp32 -> bf16 (512*1024 elems)
//   2720..2723 : v[d] = sum_c pos_emb_w[c] * pos_feature_w[c,d]
//   2724       : resolve is_molecule dtype (int32 vs bool bytes)
// (time_table is cast on the fly inside GEMM1 -- no Tbf buffer.)
// ---------------------------------------------------------------------------
__global__ __launch_bounds__(256) void prep_kernel(
    const float* __restrict__ w1,
    const float* __restrict__ w2,
    const float* __restrict__ embed_f,
    const float* __restrict__ atom_f,
    const float* __restrict__ pos_emb_w,
    const float* __restrict__ pos_feature_w,
    const void*  __restrict__ is_mol_raw,
    unsigned short* __restrict__ W1t,
    unsigned short* __restrict__ W2t,
    unsigned short* __restrict__ embed_bf,
    unsigned short* __restrict__ atom_bf,
    float* __restrict__ v,
    int*   __restrict__ is_mol_out)
{
    __shared__ float tile[32][33];
    const int blk = blockIdx.x;

    if (blk < 2048) {
        const int which = blk >> 10;                   // 0 -> w1, 1 -> w2
        const int idx = blk & 1023;
        const float* in = which ? w2 : w1;
        unsigned short* out = which ? W2t : W1t;
        const int bx = (idx & 31) * 32, by = (idx >> 5) * 32;
        const int tx = threadIdx.x & 31, ty = threadIdx.x >> 5;  // 32 x 8
        #pragma unroll
        for (int r = 0; r < 32; r += 8)
            tile[ty + r][tx] = in[(size_t)(by + ty + r) * DD + bx + tx];
        __syncthreads();
        #pragma unroll
        for (int r = 0; r < 32; r += 8)
            out[(size_t)(bx + ty + r) * DD + by + tx] = f2bf(tile[tx][ty + r]);
    } else if (blk < 2208) {
        const int e = ((blk - 2048) * 256 + threadIdx.x) * 4;    // < 160*1024
        float4 vv = *(const float4*)&embed_f[e];
        ushort4 o = { f2bf(vv.x), f2bf(vv.y), f2bf(vv.z), f2bf(vv.w) };
        *(ushort4*)&embed_bf[e] = o;
    } else if (blk < 2720) {
        const int e = ((blk - 2208) * 256 + threadIdx.x) * 4;    // < 512*1024
        float4 vv = *(const float4*)&atom_f[e];
        ushort4 o = { f2bf(vv.x), f2bf(vv.y), f2bf(vv.z), f2bf(vv.w) };
        *(ushort4*)&atom_bf[e] = o;
    } else if (blk < 2724) {
        int d = (blk - 2720) * 256 + threadIdx.x;      // < 1024
        float acc = 0.0f;
        #pragma unroll 4
        for (int c = 0; c < KK; ++c)
            acc += pos_emb_w[c] * pos_feature_w[c * DD + d];
        v[d] = acc;
    } else {
        if (threadIdx.x == 0) {
            const int* ip = (const int*)is_mol_raw;
            const unsigned char* cp = (const unsigned char*)is_mol_raw;
            bool all_bin = true;
            for (int i = 0; i < BB; ++i) {
                int x = ip[i];
                if (x != 0 && x != 1) all_bin = false;
            }
            for (int i = 0; i < BB; ++i)
                is_mol_out[i] = all_bin ? (ip[i] != 0) : (cp[i] != 0);
        }
    }
}

// ---------------------------------------------------------------------------
// bf16 MFMA GEMM, latency-optimized for 1024^2: 32x32 tiles -> grid 32x32 =
// 1024 blocks = 4 blocks/CU (16 waves/CU) for TLP latency hiding.
// 256 thr = 4 waves, wave-tile 16x16 (one f32x4 acc), BK=64.
// MODE 0: A = time_table fp32 (cast during staging, rows clamped at NTS-1;
//         junk rows >=1000 are never gathered), silu -> bf16 H.
// MODE 1: A = H bf16, bias only -> bf16 E.
// ---------------------------------------------------------------------------
template <int MODE>
__global__ __launch_bounds__(256) void mfma_gemm32(
    const void* __restrict__ Ap,
    const unsigned short* __restrict__ Bt,
    const float* __restrict__ bias,
    unsigned short* __restrict__ Cout)
{
    __shared__ __align__(16) unsigned short As[32][72];   // 144B stride
    __shared__ __align__(16) unsigned short Bs[32][72];

    const int tid  = threadIdx.x;
    const int lane = tid & 63;
    const int wave = tid >> 6;
    const int wm = wave >> 1, wn = wave & 1;
    const int quad = lane >> 4, l16 = lane & 15;
    const int mBase = blockIdx.y * 32, nBase = blockIdx.x * 32;

    f32x4 acc = {0.f, 0.f, 0.f, 0.f};

    const int r = tid >> 3, ko = (tid & 7) * 8;   // 32 rows x 64 k, 16B chunks
    const int rowB = nBase + r;
    int rowA = mBase + r;
    if (MODE == 0 && rowA >= NTS) rowA = NTS - 1;   // clamp pad rows

    for (int k0 = 0; k0 < DD; k0 += 64) {
        if (MODE == 0) {
            const float* A = (const float*)Ap;
            float4 a0 = *(const float4*)&A[(size_t)rowA * DD + k0 + ko];
            float4 a1 = *(const float4*)&A[(size_t)rowA * DD + k0 + ko + 4];
            short8 s8;
            s8[0] = f2bf(a0.x); s8[1] = f2bf(a0.y); s8[2] = f2bf(a0.z); s8[3] = f2bf(a0.w);
            s8[4] = f2bf(a1.x); s8[5] = f2bf(a1.y); s8[6] = f2bf(a1.z); s8[7] = f2bf(a1.w);
            *(short8*)&As[r][ko] = s8;
        } else {
            const unsigned short* A = (const unsigned short*)Ap;
            *(float4*)&As[r][ko] = *(const float4*)&A[(size_t)rowA * DD + k0 + ko];
        }
        *(float4*)&Bs[r][ko] = *(const float4*)&Bt[(size_t)rowB * DD + k0 + ko];
        __syncthreads();

        #pragma unroll
        for (int kk = 0; kk < 64; kk += 32) {
            short8 af = *(const short8*)&As[wm * 16 + l16][kk + quad * 8];
            short8 bf = *(const short8*)&Bs[wn * 16 + l16][kk + quad * 8];
            acc = __builtin_amdgcn_mfma_f32_16x16x32_bf16(af, bf, acc, 0, 0, 0);
        }
        __syncthreads();
    }

    // C/D layout: col = lane&15, row = quad*4 + reg  [m89-verified]
    const int col = nBase + wn * 16 + l16;
    const float bv = bias[col];
    #pragma unroll
    for (int r4 = 0; r4 < 4; ++r4) {
        const int row = mBase + wm * 16 + quad * 4 + r4;
        float val = acc[r4] + bv;
        if (MODE == 0) val = val / (1.0f + __expf(-val));   // silu
        Cout[(size_t)row * DD + col] = f2bf(val);
    }
}

// ---------------------------------------------------------------------------
// Fused attention + assembly: 1024 blocks x 256 thr; block = 8 queries of one
// batch. Keys staged once in LDS as float4(kx,ky,kz,w_s), w_s = pad? -1 : |pos|.
// No-max softmax: valid scores in (0, 0.0884] so exp can't overflow; masked
// keys contribute exactly 0 (reference: exp(NEG*SCALE - gmax) == 0).
// Phase B: bf16 tables (embed/atom/E); 128 thr x 8 dims per query row, two
// queries concurrently across thread halves.
// ---------------------------------------------------------------------------
__global__ __launch_bounds__(256) void fused_all(
    const int*   __restrict__ token_id,
    const int*   __restrict__ node_attr,
    const float* __restrict__ pos,
    const int*   __restrict__ time_step,
    const unsigned short* __restrict__ embed_bf,
    const unsigned short* __restrict__ atom_bf,
    const unsigned short* __restrict__ Ebf,   // [1024, D] bf16 (rows >=1000 junk)
    const float* __restrict__ v,              // [D] fp32
    const int*   __restrict__ is_mol,         // [B] resolved 0/1
    float* __restrict__ out)
{
    __shared__ float4 keys[LL];               // 16 KB
    __shared__ float  sS[8];

    const int blk   = blockIdx.x;             // 0..1023
    const int batch = blk >> 7;
    const int q0    = (blk & 127) << 3;       // 8 queries per block
    const int tid   = threadIdx.x;
    const int lane  = tid & 63, wave = tid >> 6;

    // ---- stage keys --------------------------------------------------------
    #pragma unroll
    for (int i = 0; i < 4; ++i) {
        const int k = tid + i * 256;
        const int t = batch * LL + k;
        const float x = pos[t * 3 + 0];
        const float y = pos[t * 3 + 1];
        const float z = pos[t * 3 + 2];
        const int tok = token_id[t];
        const float n = sqrtf(x * x + y * y + z * z);
        keys[k] = make_float4(x, y, z, tok == 0 ? -1.0f : n);
    }
    __syncthreads();

    // ---- Phase A: s per query (wave handles 2 queries) ---------------------
    #pragma unroll
    for (int qi = 0; qi < 2; ++qi) {
        const int ql = wave * 2 + qi;
        const float4 qk = keys[q0 + ql];      // broadcast read
        float lsum = 0.0f, lws = 0.0f;
        #pragma unroll 4
        for (int i = 0; i < 16; ++i) {
            const float4 kd = keys[lane + i * 64];
            const float dx = qk.x - kd.x, dy = qk.y - kd.y, dz = qk.z - kd.z;
            const float dn = sqrtf(dx * dx + dy * dy + dz * dz);
            const float e = __expf(SCALE / (dn + 1.0f));
            const bool valid = kd.w >= 0.0f;
            const float ev = valid ? e : 0.0f;
            lsum += ev;
            lws  += ev * (valid ? kd.w : 0.0f);
        }
        #pragma unroll
        for (int off = 32; off > 0; off >>= 1) {
            lsum += __shfl_xor(lsum, off);
            lws  += __shfl_xor(lws,  off);
        }
        if (lane == 0)
            sS[ql] = (qk.w < 0.0f) ? 0.0f : (lws / lsum);
    }
    __syncthreads();

    // ---- Phase B: 8 output rows; 2 queries in parallel across halves -------
    const int im   = is_mol[batch];
    const int half = tid >> 7;                 // 0/1
    const int tl   = tid & 127;
    const int j    = tl * 8;                   // 128 thr x 8 dims = 1024
    const float4 v0 = *(const float4*)&v[j];
    const float4 v1 = *(const float4*)&v[j + 4];

    #pragma unroll
    for (int qp = 0; qp < 4; ++qp) {
        const int ql  = qp * 2 + half;
        const int t   = batch * LL + q0 + ql;
        const int tok = token_id[t];
        const int ts  = time_step[t];
        const float s = sS[ql];

        float o[8];
        short8 eb = *(const short8*)&embed_bf[(size_t)tok * DD + j];
        #pragma unroll
        for (int d = 0; d < 8; ++d) o[d] = bf2f((unsigned short)eb[d]);

        if (im) {
            #pragma unroll
            for (int f = 1; f < 9; ++f) {
                const int a = node_attr[t * 9 + f];
                short8 ab = *(const short8*)&atom_bf[(size_t)a * DD + j];
                #pragma unroll
                for (int d = 0; d < 8; ++d) o[d] += bf2f((unsigned short)ab[d]);
            }
        }
        short8 er = *(const short8*)&Ebf[(size_t)ts * DD + j];
        #pragma unroll
        for (int d = 0; d < 8; ++d) o[d] += bf2f((unsigned short)er[d]);

        o[0] += s * v0.x; o[1] += s * v0.y; o[2] += s * v0.z; o[3] += s * v0.w;
        o[4] += s * v1.x; o[5] += s * v1.y; o[6] += s * v1.z; o[7] += s * v1.w;

        float4 w0 = {o[0], o[1], o[2], o[3]};
        float4 w1 = {o[4], o[5], o[6], o[7]};
        *(float4*)&out[(size_t)t * DD + j]     = w0;
        *(float4*)&out[(size_t)t * DD + j + 4] = w1;
    }

    if (tid < 8) {
        const int t = batch * LL + q0 + tid;
        out[(size_t)BB * LL * DD + t] = (keys[q0 + tid].w < 0.0f) ? 1.0f : 0.0f;
    }
}

// ---------------------------------------------------------------------------
extern "C" void kernel_launch(void* const* d_in, const int* in_sizes, int n_in,
                              void* d_out, int out_size, void* d_ws, size_t ws_size,
                              hipStream_t stream)
{
    const int*   token_id      = (const int*)  d_in[0];
    const int*   node_attr     = (const int*)  d_in[1];
    const void*  is_mol_raw    = (const void*) d_in[2];
    const float* pos           = (const float*)d_in[3];
    const int*   time_step     = (const int*)  d_in[4];
    const float* embed_table   = (const float*)d_in[5];
    const float* atom_feat     = (const float*)d_in[6];
    const float* time_table    = (const float*)d_in[7];
    const float* w1            = (const float*)d_in[8];
    const float* b1            = (const float*)d_in[9];
    const float* w2            = (const float*)d_in[10];
    const float* b2            = (const float*)d_in[11];
    const float* pos_emb_w     = (const float*)d_in[12];
    const float* pos_feature_w = (const float*)d_in[13];

    float* out = (float*)d_out;
    char*  ws  = (char*)d_ws;

    // Workspace overlay (~7.5 MB, below proven 8.43 MB):
    //   [0,2MB):      W1t bf16 (dead after GEMM1) -> Ebf bf16 (GEMM2 out)
    //   [2MB,4MB):    H bf16
    //   [4MB,6MB):    W2t bf16
    //   [6MB,+320KB): embed_bf
    //   [6.5MB,+1MB): atom_bf
    //   [7.5MB,..):   V fp32[1024], is_mol int[8]
    unsigned short* W1t      = (unsigned short*)(ws);
    unsigned short* Ebf      = (unsigned short*)(ws);
    unsigned short* H        = (unsigned short*)(ws + (2u << 20));
    unsigned short* W2t      = (unsigned short*)(ws + (4u << 20));
    unsigned short* embed_bf = (unsigned short*)(ws + (6u << 20));
    unsigned short* atom_bf  = (unsigned short*)(ws + (6u << 20) + (512u << 10));
    float*          V        = (float*)(ws + (7u << 20) + (512u << 10));
    int*            is_mol_r = (int*)(V + 1024);

    prep_kernel<<<2725, 256, 0, stream>>>(w1, w2, embed_table, atom_feat,
                                          pos_emb_w, pos_feature_w, is_mol_raw,
                                          W1t, W2t, embed_bf, atom_bf,
                                          V, is_mol_r);

    dim3 g(32, 32);
    mfma_gemm32<0><<<g, 256, 0, stream>>>((const void*)time_table, W1t, b1, H);
    mfma_gemm32<1><<<g, 256, 0, stream>>>((const void*)H,          W2t, b2, Ebf);

    fused_all<<<1024, 256, 0, stream>>>(token_id, node_attr, pos, time_step,
                                        embed_bf, atom_bf, Ebf, V,
                                        is_mol_r, out);
}

// Round 6
// 149.373 us; speedup vs baseline: 1.7450x; 1.0159x over previous
//
#include <hip/hip_runtime.h>
#include <hip/hip_bf16.h>
#include <math.h>

// Problem constants (match reference)
#define BB 8
#define LL 1024
#define DD 1024
#define KK 128
#define NTS 1000
#define VOCAB 160
#define NATOM 512
#define SCALE 0.08838834764831845f                 // 128^-0.5

typedef __attribute__((ext_vector_type(8))) short short8;   // 8 bf16 = 4 VGPRs
typedef __attribute__((ext_vector_type(4))) float f32x4;    // MFMA accumulator

__device__ __forceinline__ unsigned short f2bf(float x) {
    __hip_bfloat16 h = __float2bfloat16(x);   // RTNE
    return *reinterpret_cast<unsigned short*>(&h);
}
__device__ __forceinline__ float bf2f(unsigned short u) {
    return __uint_as_float(((unsigned int)u) << 16);
}

// ---------------------------------------------------------------------------
// Merged prep kernel (one dispatch, 2725 blocks) -- unchanged from R5:
//   0..2047    : transpose+cast w1 / w2 -> W1t/W2t [n][k] bf16
//   2048..2207 : cast embed_table fp32 -> bf16
//   2208..2719 : cast atom_feat_table fp32 -> bf16
//   2720..2723 : v[d] = sum_c pos_emb_w[c] * pos_feature_w[c,d]
//   2724       : resolve is_molecule dtype
// ---------------------------------------------------------------------------
__global__ __launch_bounds__(256) void prep_kernel(
    const float* __restrict__ w1,
    const float* __restrict__ w2,
    const float* __restrict__ embed_f,
    const float* __restrict__ atom_f,
    const float* __restrict__ pos_emb_w,
    const float* __restrict__ pos_feature_w,
    const void*  __restrict__ is_mol_raw,
    unsigned short* __restrict__ W1t,
    unsigned short* __restrict__ W2t,
    unsigned short* __restrict__ embed_bf,
    unsigned short* __restrict__ atom_bf,
    float* __restrict__ v,
    int*   __restrict__ is_mol_out)
{
    __shared__ float tile[32][33];
    const int blk = blockIdx.x;

    if (blk < 2048) {
        const int which = blk >> 10;                   // 0 -> w1, 1 -> w2
        const int idx = blk & 1023;
        const float* in = which ? w2 : w1;
        unsigned short* out = which ? W2t : W1t;
        const int bx = (idx & 31) * 32, by = (idx >> 5) * 32;
        const int tx = threadIdx.x & 31, ty = threadIdx.x >> 5;  // 32 x 8
        #pragma unroll
        for (int r = 0; r < 32; r += 8)
            tile[ty + r][tx] = in[(size_t)(by + ty + r) * DD + bx + tx];
        __syncthreads();
        #pragma unroll
        for (int r = 0; r < 32; r += 8)
            out[(size_t)(bx + ty + r) * DD + by + tx] = f2bf(tile[tx][ty + r]);
    } else if (blk < 2208) {
        const int e = ((blk - 2048) * 256 + threadIdx.x) * 4;    // < 160*1024
        float4 vv = *(const float4*)&embed_f[e];
        ushort4 o = { f2bf(vv.x), f2bf(vv.y), f2bf(vv.z), f2bf(vv.w) };
        *(ushort4*)&embed_bf[e] = o;
    } else if (blk < 2720) {
        const int e = ((blk - 2208) * 256 + threadIdx.x) * 4;    // < 512*1024
        float4 vv = *(const float4*)&atom_f[e];
        ushort4 o = { f2bf(vv.x), f2bf(vv.y), f2bf(vv.z), f2bf(vv.w) };
        *(ushort4*)&atom_bf[e] = o;
    } else if (blk < 2724) {
        int d = (blk - 2720) * 256 + threadIdx.x;      // < 1024
        float acc = 0.0f;
        #pragma unroll 4
        for (int c = 0; c < KK; ++c)
            acc += pos_emb_w[c] * pos_feature_w[c * DD + d];
        v[d] = acc;
    } else {
        if (threadIdx.x == 0) {
            const int* ip = (const int*)is_mol_raw;
            const unsigned char* cp = (const unsigned char*)is_mol_raw;
            bool all_bin = true;
            for (int i = 0; i < BB; ++i) {
                int x = ip[i];
                if (x != 0 && x != 1) all_bin = false;
            }
            for (int i = 0; i < BB; ++i)
                is_mol_out[i] = all_bin ? (ip[i] != 0) : (cp[i] != 0);
        }
    }
}

// ---------------------------------------------------------------------------
// bf16 MFMA GEMM, BK=128: 32x32 tiles, grid 32x32 = 1024 blocks = 4/CU.
// K-loop is 8 iterations (vs 16 at BK=64): half the barrier drains, and each
// staging phase has 4 (MODE0-A) / 2 (bf16) float4 loads in flight per thread,
// amortizing global-load latency over 4x the MFMA work per barrier.
// 256 thr = 4 waves, wave-tile 16x16 (one f32x4 acc).
// MODE 0: A = time_table fp32 (cast during staging, rows clamped at NTS-1;
//         junk rows >=1000 never gathered), silu -> bf16 H.
// MODE 1: A = H bf16, bias only -> bf16 E.
// ---------------------------------------------------------------------------
template <int MODE>
__global__ __launch_bounds__(256) void mfma_gemm32(
    const void* __restrict__ Ap,
    const unsigned short* __restrict__ Bt,
    const float* __restrict__ bias,
    unsigned short* __restrict__ Cout)
{
    // +8 ushort pad: row stride 272B (16B-aligned), ds_read_b128 <=2-way banks
    __shared__ __align__(16) unsigned short As[32][136];
    __shared__ __align__(16) unsigned short Bs[32][136];

    const int tid  = threadIdx.x;
    const int lane = tid & 63;
    const int wave = tid >> 6;
    const int wm = wave >> 1, wn = wave & 1;
    const int quad = lane >> 4, l16 = lane & 15;
    const int mBase = blockIdx.y * 32, nBase = blockIdx.x * 32;

    f32x4 acc = {0.f, 0.f, 0.f, 0.f};

    // Staging map: 32 rows x 128 k = 512 8-elem chunks; thread t covers
    // (row = t>>4, ko = (t&15)*8) and (row+16, same ko).
    const int r0 = tid >> 4, ko = (tid & 15) * 8;
    const int rowB0 = nBase + r0,      rowB1 = nBase + r0 + 16;
    int rowA0 = mBase + r0,            rowA1 = mBase + r0 + 16;
    if (MODE == 0) {                                   // clamp pad rows
        if (rowA0 >= NTS) rowA0 = NTS - 1;
        if (rowA1 >= NTS) rowA1 = NTS - 1;
    }

    for (int k0 = 0; k0 < DD; k0 += 128) {
        if (MODE == 0) {
            const float* A = (const float*)Ap;
            float4 a00 = *(const float4*)&A[(size_t)rowA0 * DD + k0 + ko];
            float4 a01 = *(const float4*)&A[(size_t)rowA0 * DD + k0 + ko + 4];
            float4 a10 = *(const float4*)&A[(size_t)rowA1 * DD + k0 + ko];
            float4 a11 = *(const float4*)&A[(size_t)rowA1 * DD + k0 + ko + 4];
            short8 s0, s1;
            s0[0]=f2bf(a00.x); s0[1]=f2bf(a00.y); s0[2]=f2bf(a00.z); s0[3]=f2bf(a00.w);
            s0[4]=f2bf(a01.x); s0[5]=f2bf(a01.y); s0[6]=f2bf(a01.z); s0[7]=f2bf(a01.w);
            s1[0]=f2bf(a10.x); s1[1]=f2bf(a10.y); s1[2]=f2bf(a10.z); s1[3]=f2bf(a10.w);
            s1[4]=f2bf(a11.x); s1[5]=f2bf(a11.y); s1[6]=f2bf(a11.z); s1[7]=f2bf(a11.w);
            *(short8*)&As[r0][ko]      = s0;
            *(short8*)&As[r0 + 16][ko] = s1;
        } else {
            const unsigned short* A = (const unsigned short*)Ap;
            float4 a0 = *(const float4*)&A[(size_t)rowA0 * DD + k0 + ko];
            float4 a1 = *(const float4*)&A[(size_t)rowA1 * DD + k0 + ko];
            *(float4*)&As[r0][ko]      = a0;
            *(float4*)&As[r0 + 16][ko] = a1;
        }
        float4 b0 = *(const float4*)&Bt[(size_t)rowB0 * DD + k0 + ko];
        float4 b1 = *(const float4*)&Bt[(size_t)rowB1 * DD + k0 + ko];
        *(float4*)&Bs[r0][ko]      = b0;
        *(float4*)&Bs[r0 + 16][ko] = b1;
        __syncthreads();

        #pragma unroll
        for (int kk = 0; kk < 128; kk += 32) {
            short8 af = *(const short8*)&As[wm * 16 + l16][kk + quad * 8];
            short8 bf = *(const short8*)&Bs[wn * 16 + l16][kk + quad * 8];
            acc = __builtin_amdgcn_mfma_f32_16x16x32_bf16(af, bf, acc, 0, 0, 0);
        }
        __syncthreads();
    }

    // C/D layout: col = lane&15, row = quad*4 + reg  [m89-verified]
    const int col = nBase + wn * 16 + l16;
    const float bv = bias[col];
    #pragma unroll
    for (int r4 = 0; r4 < 4; ++r4) {
        const int row = mBase + wm * 16 + quad * 4 + r4;
        float val = acc[r4] + bv;
        if (MODE == 0) val = val / (1.0f + __expf(-val));   // silu
        Cout[(size_t)row * DD + col] = f2bf(val);
    }
}

// ---------------------------------------------------------------------------
// Fused attention + assembly -- unchanged from R5 (passing).
// ---------------------------------------------------------------------------
__global__ __launch_bounds__(256) void fused_all(
    const int*   __restrict__ token_id,
    const int*   __restrict__ node_attr,
    const float* __restrict__ pos,
    const int*   __restrict__ time_step,
    const unsigned short* __restrict__ embed_bf,
    const unsigned short* __restrict__ atom_bf,
    const unsigned short* __restrict__ Ebf,   // [1024, D] bf16 (rows >=1000 junk)
    const float* __restrict__ v,              // [D] fp32
    const int*   __restrict__ is_mol,         // [B] resolved 0/1
    float* __restrict__ out)
{
    __shared__ float4 keys[LL];               // 16 KB
    __shared__ float  sS[8];

    const int blk   = blockIdx.x;             // 0..1023
    const int batch = blk >> 7;
    const int q0    = (blk & 127) << 3;       // 8 queries per block
    const int tid   = threadIdx.x;
    const int lane  = tid & 63, wave = tid >> 6;

    // ---- stage keys --------------------------------------------------------
    #pragma unroll
    for (int i = 0; i < 4; ++i) {
        const int k = tid + i * 256;
        const int t = batch * LL + k;
        const float x = pos[t * 3 + 0];
        const float y = pos[t * 3 + 1];
        const float z = pos[t * 3 + 2];
        const int tok = token_id[t];
        const float n = sqrtf(x * x + y * y + z * z);
        keys[k] = make_float4(x, y, z, tok == 0 ? -1.0f : n);
    }
    __syncthreads();

    // ---- Phase A: s per query (wave handles 2 queries) ---------------------
    #pragma unroll
    for (int qi = 0; qi < 2; ++qi) {
        const int ql = wave * 2 + qi;
        const float4 qk = keys[q0 + ql];      // broadcast read
        float lsum = 0.0f, lws = 0.0f;
        #pragma unroll 4
        for (int i = 0; i < 16; ++i) {
            const float4 kd = keys[lane + i * 64];
            const float dx = qk.x - kd.x, dy = qk.y - kd.y, dz = qk.z - kd.z;
            const float dn = sqrtf(dx * dx + dy * dy + dz * dz);
            const float e = __expf(SCALE / (dn + 1.0f));
            const bool valid = kd.w >= 0.0f;
            const float ev = valid ? e : 0.0f;
            lsum += ev;
            lws  += ev * (valid ? kd.w : 0.0f);
        }
        #pragma unroll
        for (int off = 32; off > 0; off >>= 1) {
            lsum += __shfl_xor(lsum, off);
            lws  += __shfl_xor(lws,  off);
        }
        if (lane == 0)
            sS[ql] = (qk.w < 0.0f) ? 0.0f : (lws / lsum);
    }
    __syncthreads();

    // ---- Phase B: 8 output rows; 2 queries in parallel across halves -------
    const int im   = is_mol[batch];
    const int half = tid >> 7;                 // 0/1
    const int tl   = tid & 127;
    const int j    = tl * 8;                   // 128 thr x 8 dims = 1024
    const float4 v0 = *(const float4*)&v[j];
    const float4 v1 = *(const float4*)&v[j + 4];

    #pragma unroll
    for (int qp = 0; qp < 4; ++qp) {
        const int ql  = qp * 2 + half;
        const int t   = batch * LL + q0 + ql;
        const int tok = token_id[t];
        const int ts  = time_step[t];
        const float s = sS[ql];

        float o[8];
        short8 eb = *(const short8*)&embed_bf[(size_t)tok * DD + j];
        #pragma unroll
        for (int d = 0; d < 8; ++d) o[d] = bf2f((unsigned short)eb[d]);

        if (im) {
            #pragma unroll
            for (int f = 1; f < 9; ++f) {
                const int a = node_attr[t * 9 + f];
                short8 ab = *(const short8*)&atom_bf[(size_t)a * DD + j];
                #pragma unroll
                for (int d = 0; d < 8; ++d) o[d] += bf2f((unsigned short)ab[d]);
            }
        }
        short8 er = *(const short8*)&Ebf[(size_t)ts * DD + j];
        #pragma unroll
        for (int d = 0; d < 8; ++d) o[d] += bf2f((unsigned short)er[d]);

        o[0] += s * v0.x; o[1] += s * v0.y; o[2] += s * v0.z; o[3] += s * v0.w;
        o[4] += s * v1.x; o[5] += s * v1.y; o[6] += s * v1.z; o[7] += s * v1.w;

        float4 w0 = {o[0], o[1], o[2], o[3]};
        float4 w1 = {o[4], o[5], o[6], o[7]};
        *(float4*)&out[(size_t)t * DD + j]     = w0;
        *(float4*)&out[(size_t)t * DD + j + 4] = w1;
    }

    if (tid < 8) {
        const int t = batch * LL + q0 + tid;
        out[(size_t)BB * LL * DD + t] = (keys[q0 + tid].w < 0.0f) ? 1.0f : 0.0f;
    }
}

// ---------------------------------------------------------------------------
extern "C" void kernel_launch(void* const* d_in, const int* in_sizes, int n_in,
                              void* d_out, int out_size, void* d_ws, size_t ws_size,
                              hipStream_t stream)
{
    const int*   token_id      = (const int*)  d_in[0];
    const int*   node_attr     = (const int*)  d_in[1];
    const void*  is_mol_raw    = (const void*) d_in[2];
    const float* pos           = (const float*)d_in[3];
    const int*   time_step     = (const int*)  d_in[4];
    const float* embed_table   = (const float*)d_in[5];
    const float* atom_feat     = (const float*)d_in[6];
    const float* time_table    = (const float*)d_in[7];
    const float* w1            = (const float*)d_in[8];
    const float* b1            = (const float*)d_in[9];
    const float* w2            = (const float*)d_in[10];
    const float* b2            = (const float*)d_in[11];
    const float* pos_emb_w     = (const float*)d_in[12];
    const float* pos_feature_w = (const float*)d_in[13];

    float* out = (float*)d_out;
    char*  ws  = (char*)d_ws;

    // Workspace overlay (~7.5 MB) -- unchanged from R5:
    //   [0,2MB):      W1t bf16 (dead after GEMM1) -> Ebf bf16 (GEMM2 out)
    //   [2MB,4MB):    H bf16
    //   [4MB,6MB):    W2t bf16
    //   [6MB,+320KB): embed_bf
    //   [6.5MB,+1MB): atom_bf
    //   [7.5MB,..):   V fp32[1024], is_mol int[8]
    unsigned short* W1t      = (unsigned short*)(ws);
    unsigned short* Ebf      = (unsigned short*)(ws);
    unsigned short* H        = (unsigned short*)(ws + (2u << 20));
    unsigned short* W2t      = (unsigned short*)(ws + (4u << 20));
    unsigned short* embed_bf = (unsigned short*)(ws + (6u << 20));
    unsigned short* atom_bf  = (unsigned short*)(ws + (6u << 20) + (512u << 10));
    float*          V        = (float*)(ws + (7u << 20) + (512u << 10));
    int*            is_mol_r = (int*)(V + 1024);

    prep_kernel<<<2725, 256, 0, stream>>>(w1, w2, embed_table, atom_feat,
                                          pos_emb_w, pos_feature_w, is_mol_raw,
                                          W1t, W2t, embed_bf, atom_bf,
                                          V, is_mol_r);

    dim3 g(32, 32);
    mfma_gemm32<0><<<g, 256, 0, stream>>>((const void*)time_table, W1t, b1, H);
    mfma_gemm32<1><<<g, 256, 0, stream>>>((const void*)H,          W2t, b2, Ebf);

    fused_all<<<1024, 256, 0, stream>>>(token_id, node_attr, pos, time_step,
                                        embed_bf, atom_bf, Ebf, V,
                                        is_mol_r, out);
}